// Round 9
// baseline (372.613 us; speedup 1.0000x reference)
//
#include <hip/hip_runtime.h>

#define EMBED 1024
#define SEQ   2048
#define BATCH 4
#define HEADS 16

typedef __attribute__((ext_vector_type(8))) short short8;   // 8 bf16 in 4 VGPRs
typedef __attribute__((ext_vector_type(4))) float floatx4;
typedef __attribute__((ext_vector_type(16))) float floatx16;

#define MFMA16(a, b, c) __builtin_amdgcn_mfma_f32_16x16x32_bf16((a), (b), (c), 0, 0, 0)
#define MFMA32(a, b, c) __builtin_amdgcn_mfma_f32_32x32x16_bf16((a), (b), (c), 0, 0, 0)
#define ATT_SCALE (0.125f * 1.44269504088896340736f)   // 1/sqrt(64) * log2(e), folded into Q

static __device__ __forceinline__ unsigned short f2bf(float f) {
  union { float f; unsigned int u; } v; v.f = f;
  unsigned int u = v.u;
  u += 0x7fffu + ((u >> 16) & 1u);       // RNE
  return (unsigned short)(u >> 16);
}

// v_cvt_pk_bf16_f32: dst.lo16 = bf16(lo), dst.hi16 = bf16(hi)  (RNE)
static __device__ __forceinline__ unsigned cvtpk(float lo, float hi) {
  unsigned r;
  asm("v_cvt_pk_bf16_f32 %0, %1, %2" : "=v"(r) : "v"(lo), "v"(hi));
  return r;
}

static __device__ __forceinline__ void async16(const unsigned short* g, unsigned short* l) {
  __builtin_amdgcn_global_load_lds(
      (const __attribute__((address_space(1))) void*)g,
      (__attribute__((address_space(3))) void*)l, 16, 0, 0);
}

// ---------------- fused prep: hidden fp32->bf16 (blocks 0..4095) +
//                  W[k][n]->WT[n][k] bf16 for Wq,Wk,Wv,Wp (blocks 4096..5119) ---
__global__ __launch_bounds__(256) void k_prep(const float* __restrict__ hid,
                                              unsigned short* __restrict__ hidA,
                                              const float* __restrict__ Wq, const float* __restrict__ Wk,
                                              const float* __restrict__ Wv, const float* __restrict__ Wp,
                                              unsigned short* __restrict__ WT) {
  __shared__ unsigned short tile[64][65];
  const int bid = blockIdx.x, tid = threadIdx.x;
  if (bid < 4096) {                       // cvt: 8 floats / thread
    int i = bid * 256 + tid;
    const float4* s = (const float4*)hid;
    float4 a = s[i * 2], b = s[i * 2 + 1];
    uint4 o;
    o.x = (unsigned)f2bf(a.x) | ((unsigned)f2bf(a.y) << 16);
    o.y = (unsigned)f2bf(a.z) | ((unsigned)f2bf(a.w) << 16);
    o.z = (unsigned)f2bf(b.x) | ((unsigned)f2bf(b.y) << 16);
    o.w = (unsigned)f2bf(b.z) | ((unsigned)f2bf(b.w) << 16);
    ((uint4*)hidA)[i] = o;
    return;
  }
  const int idx = bid - 4096;
  const int z = idx >> 8, rem = idx & 255;
  const float* src = (z == 0) ? Wq : (z == 1) ? Wk : (z == 2) ? Wv : Wp;
  unsigned short* dst = WT + (size_t)z * EMBED * EMBED;
  const int k0 = (rem & 15) * 64, n0 = (rem >> 4) * 64;
  for (int i = tid; i < 4096; i += 256) {
    int r = i >> 6, c = i & 63;
    tile[c][r] = f2bf(src[(size_t)(k0 + r) * EMBED + n0 + c]);
  }
  __syncthreads();
  for (int i = tid; i < 4096; i += 256) {
    int r = i >> 6, c = i & 63;
    dst[(size_t)(n0 + r) * EMBED + k0 + c] = tile[r][c];
  }
}

// ---------------- QKV GEMM (128x128, proven structure) + fused V-transpose ----
// by < 16 : C[m][n0..] = hidA[m,:].WT_qk[n,:] + bias  (Q cols pre-scaled)
// by >= 16: V^T by operand symmetry (rows = d, cols = l); writes VT directly.
__global__ __launch_bounds__(256) void k_gemm_qkv(const unsigned short* __restrict__ A,
                                                  const unsigned short* __restrict__ BT,
                                                  const float* __restrict__ bq,
                                                  const float* __restrict__ bk,
                                                  const float* __restrict__ bv,
                                                  unsigned short* __restrict__ C,
                                                  unsigned short* __restrict__ VT) {
  __shared__ unsigned short Als[128 * 64];
  __shared__ unsigned short Bls[128 * 64];
  const int tid = threadIdx.x;
  const int by = blockIdx.y;
  const bool vmode = (by >= 16);
  const int arow0 = vmode ? (by - 16) * 128 : blockIdx.x * 128;
  const int brow0 = vmode ? blockIdx.x * 128 : by * 128;
  const int w = tid >> 6, lane = tid & 63, l16 = lane & 15, quad = lane >> 4;
  const int l7 = l16 & 7;
  const int wrow = (w >> 1) * 64, wcol = (w & 1) * 64;

  floatx4 acc[4][4];
#pragma unroll
  for (int i = 0; i < 4; ++i)
#pragma unroll
    for (int j = 0; j < 4; ++j) acc[i][j] = {0.f, 0.f, 0.f, 0.f};

  const int srow = tid >> 3;
  const int scol = (((tid & 7) ^ (srow & 7)) * 8);
  const unsigned short* Arow = vmode ? (BT + (size_t)2 * EMBED * EMBED) : A;
  const unsigned short* Brow = vmode ? A : BT;
  const unsigned short* Ap = Arow + (size_t)(arow0 + srow) * EMBED + scol;
  const unsigned short* Bp = Brow + (size_t)(brow0 + srow) * EMBED + scol;

  int ab[2], bb[2];
#pragma unroll
  for (int kc = 0; kc < 2; ++kc) {
    ab[kc] = (wrow + l16) * 64 + (((4 * kc + quad) ^ l7) << 3);
    bb[kc] = (wcol + l16) * 64 + (((4 * kc + quad) ^ l7) << 3);
  }

  for (int kt = 0; kt < 16; ++kt) {
    const int k0 = kt * 64;
#pragma unroll
    for (int i = 0; i < 4; ++i)
      async16(Ap + k0 + (size_t)i * 32 * EMBED, Als + i * 2048 + tid * 8);
#pragma unroll
    for (int i = 0; i < 4; ++i)
      async16(Bp + k0 + (size_t)i * 32 * EMBED, Bls + i * 2048 + tid * 8);
    __syncthreads();
    short8 af[4][2], bf[4][2];
#pragma unroll
    for (int mt = 0; mt < 4; ++mt)
#pragma unroll
      for (int kc = 0; kc < 2; ++kc)
        af[mt][kc] = *(const short8*)(Als + ab[kc] + mt * 1024);
#pragma unroll
    for (int nt = 0; nt < 4; ++nt)
#pragma unroll
      for (int kc = 0; kc < 2; ++kc)
        bf[nt][kc] = *(const short8*)(Bls + bb[kc] + nt * 1024);
#pragma unroll
    for (int kc = 0; kc < 2; ++kc)
#pragma unroll
      for (int mt = 0; mt < 4; ++mt)
#pragma unroll
        for (int nt = 0; nt < 4; ++nt)
          acc[mt][nt] = MFMA16(af[mt][kc], bf[nt][kc], acc[mt][nt]);
    __syncthreads();
  }

  if (!vmode) {
    const int n0 = brow0;
    const float* bsel = (n0 < 1024) ? bq : bk;
    const float scl = (n0 < 1024) ? ATT_SCALE : 1.0f;
    const int nb = n0 & 1023;
    float bias[4];
#pragma unroll
    for (int nt = 0; nt < 4; ++nt) bias[nt] = bsel[nb + wcol + nt * 16 + l16];
#pragma unroll
    for (int mt = 0; mt < 4; ++mt)
#pragma unroll
      for (int r = 0; r < 4; ++r) {
        int gm = arow0 + wrow + mt * 16 + quad * 4 + r;
        size_t base = (size_t)gm * 3072 + n0 + wcol;
#pragma unroll
        for (int nt = 0; nt < 4; ++nt)
          C[base + nt * 16 + l16] = f2bf((acc[mt][nt][r] + bias[nt]) * scl);
      }
  } else {
    // rows = d-global, cols = l-global; VT[(b*16+h)*64 + d][l]
#pragma unroll
    for (int mt = 0; mt < 4; ++mt)
#pragma unroll
      for (int r = 0; r < 4; ++r) {
        const int drow = arow0 + wrow + mt * 16 + quad * 4 + r;   // 0..1023
        const float bias = bv[drow];
        const int cg0 = brow0 + wcol;                             // col base (l-global)
        const int b = cg0 >> 11;                                  // constant per block
        const size_t base = ((size_t)((b * 16 + (drow >> 6)) * 64 + (drow & 63))) * SEQ
                            + (cg0 & 2047);
#pragma unroll
        for (int nt = 0; nt < 4; ++nt)
          VT[base + nt * 16 + l16] = f2bf(acc[mt][nt][r] + bias);
      }
  }
}

// QK step: S[kvg][qg] = K-tile(LDS) x Q(frags), swapped-operand 32x32
static __device__ __forceinline__ void qk_step(const unsigned short* Kc,
                                               const short8 qf[2][4],
                                               int l32, int hi,
                                               floatx16 S[2][2]) {
#pragma unroll
  for (int kvg = 0; kvg < 2; ++kvg) {
    short8 kf[4];
#pragma unroll
    for (int ds = 0; ds < 4; ++ds) {
      const int row = kvg * 32 + l32;
      kf[ds] = *(const short8*)(Kc + row * 64 + (((ds * 2 + hi) ^ (row & 7)) << 3));
    }
#pragma unroll
    for (int qg = 0; qg < 2; ++qg) {
      floatx16 s;
#pragma unroll
      for (int c = 0; c < 16; ++c) s[c] = 0.f;
#pragma unroll
      for (int ds = 0; ds < 4; ++ds) s = MFMA32(kf[ds], qf[qg][ds], s);
      S[kvg][qg] = s;
    }
  }
}

// ---------------- attention v14: v10 + software-pipelined S (T15) -------------
// Iteration kt: exp2/pack(S of tile kt) -> PV(tile kt) -> QK(tile kt+1 -> S).
// K staged TWO ahead (K[kt+2]->Kls[kt&1]), V one ahead (V[kt+1]->Vls[(kt+1)&1]).
// Per-tile math order unchanged -> bit-identical output.
__global__ __launch_bounds__(256, 2) void k_attn(const unsigned short* __restrict__ QKV,
                                                 const unsigned short* __restrict__ VT,
                                                 unsigned short* __restrict__ CTX) {
  const int bh = blockIdx.x, qt = blockIdx.y;
  const int b = bh >> 4, h = bh & 15;
  const int tid = threadIdx.x;
  const int w = tid >> 6, lane = tid & 63;
  const int l32 = lane & 31, hi = lane >> 5;

  __shared__ unsigned short Kls[2][64 * 64];   // [buf][kv][d]  xor-chunk swizzled
  __shared__ unsigned short Vls[2][64 * 64];   // [buf][d][kv]  xor-chunk swizzled
  __shared__ float rsls[4][64];                // per-wave row sums

  const unsigned short* Qb = QKV + (size_t)(b * SEQ + qt * 256 + w * 64) * 3072 + h * 64;
  const unsigned short* Kb = QKV + (size_t)(b * SEQ) * 3072 + 1024 + h * 64;
  const unsigned short* Vb = VT + (size_t)bh * 64 * SEQ;

  // Q fragments (B-operand of swapped QK): qf[qg][ds] holds
  // Q[q = qg*32 + l32][d = ds*16 + hi*8 + j]  (pre-scaled by ATT_SCALE)
  short8 qf[2][4];
#pragma unroll
  for (int qg = 0; qg < 2; ++qg)
#pragma unroll
    for (int ds = 0; ds < 4; ++ds)
      qf[qg][ds] = *(const short8*)(Qb + (size_t)(qg * 32 + l32) * 3072 + ds * 16 + hi * 8);

  floatx16 o[2][2];
  floatx16 S[2][2];
  float rs[2] = {0.f, 0.f};
#pragma unroll
  for (int qg = 0; qg < 2; ++qg)
#pragma unroll
    for (int dg = 0; dg < 2; ++dg)
#pragma unroll
      for (int c = 0; c < 16; ++c) o[qg][dg][c] = 0.f;

  const int srow = tid >> 3;                              // 0..31
  const int scol = (((tid & 7) ^ (srow & 7)) * 8);        // swizzled source chunk

  // prologue: stage K[0],V[0] -> buf0, K[1] -> buf1
  async16(Kb + (size_t)srow * 3072 + scol, Kls[0] + tid * 8);
  async16(Kb + (size_t)(32 + srow) * 3072 + scol, Kls[0] + 2048 + tid * 8);
  async16(Vb + (size_t)srow * SEQ + scol, Vls[0] + tid * 8);
  async16(Vb + (size_t)(32 + srow) * SEQ + scol, Vls[0] + 2048 + tid * 8);
  async16(Kb + (size_t)(64 + srow) * 3072 + scol, Kls[1] + tid * 8);
  async16(Kb + (size_t)(64 + 32 + srow) * 3072 + scol, Kls[1] + 2048 + tid * 8);
  __syncthreads();

  // QK tile 0 -> S (reads Kls[0])
  qk_step(Kls[0], qf, l32, hi, S);
  __syncthreads();   // all waves done with Kls[0] before kt=0 stages K[2] there

  for (int kt = 0; kt < 32; ++kt) {
    const int cur = kt & 1;
    // stage V[kt+1] -> Vls[cur^1]  (PV this iter reads Vls[cur])
    if (kt < 31) {
      const int vn = (kt + 1) * 64;
      unsigned short* Vd = Vls[cur ^ 1];
      async16(Vb + (size_t)srow * SEQ + vn + scol, Vd + tid * 8);
      async16(Vb + (size_t)(32 + srow) * SEQ + vn + scol, Vd + 2048 + tid * 8);
    }
    // stage K[kt+2] -> Kls[cur]  (QK this iter reads Kls[cur^1])
    if (kt < 30) {
      const int kn = (kt + 2) * 64;
      unsigned short* Kd = Kls[cur];
      async16(Kb + (size_t)(kn + srow) * 3072 + scol, Kd + tid * 8);
      async16(Kb + (size_t)(kn + 32 + srow) * 3072 + scol, Kd + 2048 + tid * 8);
    }

    // exp2 + pack of tile kt (reads S; independent of this iter's QK below)
    short8 pa[2][4];   // [qg][ks] packed P fragments (PV A-operand)
#pragma unroll
    for (int kvg = 0; kvg < 2; ++kvg)
#pragma unroll
      for (int qg = 0; qg < 2; ++qg) {
        float p[16];
#pragma unroll
        for (int c = 0; c < 16; ++c) p[c] = __builtin_amdgcn_exp2f(S[kvg][qg][c]);
        rs[qg] += (((p[0] + p[1]) + (p[2] + p[3])) + ((p[4] + p[5]) + (p[6] + p[7])))
                + (((p[8] + p[9]) + (p[10] + p[11])) + ((p[12] + p[13]) + (p[14] + p[15])));
#pragma unroll
        for (int half = 0; half < 2; ++half) {   // ks = kvg*2 + half
          unsigned w0 = cvtpk(p[half * 8 + 0], p[half * 8 + 1]);
          unsigned w1 = cvtpk(p[half * 8 + 2], p[half * 8 + 3]);
          unsigned w2 = cvtpk(p[half * 8 + 4], p[half * 8 + 5]);
          unsigned w3 = cvtpk(p[half * 8 + 6], p[half * 8 + 7]);
          asm("v_permlane32_swap_b32 %0, %1" : "+v"(w0), "+v"(w2));
          asm("v_permlane32_swap_b32 %0, %1" : "+v"(w1), "+v"(w3));
          union { unsigned u[4]; short8 s8; } pk;
          pk.u[0] = w0; pk.u[1] = w1; pk.u[2] = w2; pk.u[3] = w3;
          pa[qg][kvg * 2 + half] = pk.s8;
        }
      }

    // O += P V   (V[kt] in Vls[cur])
#pragma unroll
    for (int dg = 0; dg < 2; ++dg) {
      short8 vf[4];
#pragma unroll
      for (int ks = 0; ks < 4; ++ks) {
        const int row = dg * 32 + l32;
        vf[ks] = *(const short8*)(Vls[cur] + row * 64 + (((ks * 2 + hi) ^ (row & 7)) << 3));
      }
#pragma unroll
      for (int qg = 0; qg < 2; ++qg)
#pragma unroll
        for (int ks = 0; ks < 4; ++ks)
          o[qg][dg] = MFMA32(pa[qg][ks], vf[ks], o[qg][dg]);
    }

    // QK tile kt+1 -> S  (K[kt+1] in Kls[cur^1]; overlaps pack/PV above)
    if (kt < 31) qk_step(Kls[cur ^ 1], qf, l32, hi, S);

    // single barrier: drains this iter's stages and protects staged buffers
    __syncthreads();
  }

  // lanes l and l+32 hold the same q; combine, publish per-q sums via LDS
  rs[0] += __shfl_xor(rs[0], 32);
  rs[1] += __shfl_xor(rs[1], 32);
  if (lane < 32) {
    rsls[w][l32] = rs[0];
    rsls[w][32 + l32] = rs[1];
  }
  // same-wave LDS readback; per-wave in-order, compiler inserts the lgkm wait

  // write ctx[b*SEQ + q][h*64 + d] bf16; O rows: q = (j&3)+8*(j>>2)+4*hi (+32qg)
#pragma unroll
  for (int qg = 0; qg < 2; ++qg)
#pragma unroll
    for (int j = 0; j < 16; ++j) {
      const int rl = (j & 3) + 8 * (j >> 2) + 4 * hi;
      const float inv = 1.f / rsls[w][qg * 32 + rl];
      const int gq = b * SEQ + qt * 256 + w * 64 + qg * 32 + rl;
      const size_t base = (size_t)gq * EMBED + h * 64;
#pragma unroll
      for (int dg = 0; dg < 2; ++dg)
        CTX[base + dg * 32 + l32] = f2bf(o[qg][dg][j] * inv);
    }
}

// ---------------- proj GEMM + bias + residual -> fp32 x, FUSED LayerNorm ------
// Last-block-finisher: after storing its X slice, each block threadfences and
// bumps cnt[bm]; the 8th (last) block for that 128-row band re-fences and LNs
// the band in place (4 waves x 32 rows, 64-lane shfl reduce).  Kills the k_ln
// dispatch (~10us launch gap + 11us serial kernel) for ~3us of finisher tail.
__global__ __launch_bounds__(256) void k_gemm_proj(const unsigned short* __restrict__ A,
                                                   const unsigned short* __restrict__ BT,
                                                   const float* __restrict__ bp,
                                                   const float* __restrict__ hid,
                                                   float* __restrict__ X,
                                                   const float* __restrict__ gamma,
                                                   const float* __restrict__ beta,
                                                   int* __restrict__ cnt) {
  __shared__ unsigned short Als[128 * 64];
  __shared__ unsigned short Bls[128 * 64];
  const int tid = threadIdx.x;
  const int m0 = blockIdx.x * 128, n0 = blockIdx.y * 128;
  const int w = tid >> 6, lane = tid & 63, l16 = lane & 15, quad = lane >> 4;
  const int l7 = l16 & 7;
  const int wrow = (w >> 1) * 64, wcol = (w & 1) * 64;

  floatx4 acc[4][4];
#pragma unroll
  for (int i = 0; i < 4; ++i)
#pragma unroll
    for (int j = 0; j < 4; ++j) acc[i][j] = {0.f, 0.f, 0.f, 0.f};

  const int srow = tid >> 3;
  const int scol = (((tid & 7) ^ (srow & 7)) * 8);
  const unsigned short* Ap = A + (size_t)(m0 + srow) * EMBED + scol;
  const unsigned short* Bp = BT + (size_t)(n0 + srow) * EMBED + scol;

  int ab[2], bb[2];
#pragma unroll
  for (int kc = 0; kc < 2; ++kc) {
    ab[kc] = (wrow + l16) * 64 + (((4 * kc + quad) ^ l7) << 3);
    bb[kc] = (wcol + l16) * 64 + (((4 * kc + quad) ^ l7) << 3);
  }

  for (int kt = 0; kt < 16; ++kt) {
    const int k0 = kt * 64;
#pragma unroll
    for (int i = 0; i < 4; ++i)
      async16(Ap + k0 + (size_t)i * 32 * EMBED, Als + i * 2048 + tid * 8);
#pragma unroll
    for (int i = 0; i < 4; ++i)
      async16(Bp + k0 + (size_t)i * 32 * EMBED, Bls + i * 2048 + tid * 8);
    __syncthreads();
    short8 af[4][2], bf[4][2];
#pragma unroll
    for (int mt = 0; mt < 4; ++mt)
#pragma unroll
      for (int kc = 0; kc < 2; ++kc)
        af[mt][kc] = *(const short8*)(Als + ab[kc] + mt * 1024);
#pragma unroll
    for (int nt = 0; nt < 4; ++nt)
#pragma unroll
      for (int kc = 0; kc < 2; ++kc)
        bf[nt][kc] = *(const short8*)(Bls + bb[kc] + nt * 1024);
#pragma unroll
    for (int kc = 0; kc < 2; ++kc)
#pragma unroll
      for (int mt = 0; mt < 4; ++mt)
#pragma unroll
        for (int nt = 0; nt < 4; ++nt)
          acc[mt][nt] = MFMA16(af[mt][kc], bf[nt][kc], acc[mt][nt]);
    __syncthreads();
  }

  float bias[4];
#pragma unroll
  for (int nt = 0; nt < 4; ++nt) bias[nt] = bp[n0 + wcol + nt * 16 + l16];
#pragma unroll
  for (int mt = 0; mt < 4; ++mt)
#pragma unroll
    for (int r = 0; r < 4; ++r) {
      int gm = m0 + wrow + mt * 16 + quad * 4 + r;
      size_t base = (size_t)gm * EMBED + n0 + wcol;
#pragma unroll
      for (int nt = 0; nt < 4; ++nt) {
        size_t idx = base + nt * 16 + l16;
        X[idx] = acc[mt][nt][r] + bias[nt] + hid[idx];
      }
    }

  // ---- last-block finisher: LayerNorm rows m0..m0+127 in place ----
  __threadfence();                       // release: X stores visible device-wide
  __shared__ int lastdone;
  if (tid == 0) lastdone = (atomicAdd(&cnt[blockIdx.x], 1) == 7);
  __syncthreads();
  if (!lastdone) return;
  __threadfence();                       // acquire: see all 8 blocks' X stores

  for (int r = w; r < 128; r += 4) {     // wave w handles rows w, w+4, ...
    float* row = X + (size_t)(m0 + r) * EMBED;
    float4 xv[4];
    float s = 0.f, q = 0.f;
#pragma unroll
    for (int k = 0; k < 4; ++k) {
      xv[k] = *(const float4*)(row + lane * 4 + k * 256);
      s += (xv[k].x + xv[k].y) + (xv[k].z + xv[k].w);
      q += (xv[k].x * xv[k].x + xv[k].y * xv[k].y) + (xv[k].z * xv[k].z + xv[k].w * xv[k].w);
    }
#pragma unroll
    for (int off = 1; off < 64; off <<= 1) {
      s += __shfl_xor(s, off);
      q += __shfl_xor(q, off);
    }
    const float mean = s * (1.f / 1024.f);
    const float var = q * (1.f / 1024.f) - mean * mean;
    const float rstd = rsqrtf(var + 1e-8f);
#pragma unroll
    for (int k = 0; k < 4; ++k) {
      const float4 g = *(const float4*)(gamma + lane * 4 + k * 256);
      const float4 be = *(const float4*)(beta + lane * 4 + k * 256);
      xv[k].x = (xv[k].x - mean) * rstd * g.x + be.x;
      xv[k].y = (xv[k].y - mean) * rstd * g.y + be.y;
      xv[k].z = (xv[k].z - mean) * rstd * g.z + be.z;
      xv[k].w = (xv[k].w - mean) * rstd * g.w + be.w;
      *(float4*)(row + lane * 4 + k * 256) = xv[k];
    }
  }
}

extern "C" void kernel_launch(void* const* d_in, const int* in_sizes, int n_in,
                              void* d_out, int out_size, void* d_ws, size_t ws_size,
                              hipStream_t stream) {
  const float* hid   = (const float*)d_in[0];
  const float* Wq    = (const float*)d_in[1];
  const float* bq    = (const float*)d_in[2];
  const float* Wk    = (const float*)d_in[3];
  const float* bk    = (const float*)d_in[4];
  const float* Wv    = (const float*)d_in[5];
  const float* bv    = (const float*)d_in[6];
  const float* Wp    = (const float*)d_in[7];
  const float* bp    = (const float*)d_in[8];
  const float* gamma = (const float*)d_in[9];
  const float* beta  = (const float*)d_in[10];
  float* out = (float*)d_out;

  char* ws = (char*)d_ws;
  unsigned short* hidA = (unsigned short*)ws;                          // 16 MB  [8192][1024]
  unsigned short* WT   = (unsigned short*)(ws + (size_t)(16 << 20));   //  8 MB  [4096][1024]
  unsigned short* QKV  = (unsigned short*)(ws + (size_t)(24 << 20));   // 48 MB  [8192][3072] (V third unused)
  unsigned short* VT   = (unsigned short*)(ws + (size_t)(72 << 20));   // 16 MB  [64][64][2048]
  unsigned short* CTX  = (unsigned short*)(ws + (size_t)(88 << 20));   // 16 MB  [8192][1024]
  int*            CNT  = (int*)(ws + (size_t)(120 << 20));             // 256 B  [64]

  hipMemsetAsync(CNT, 0, 64 * sizeof(int), stream);
  k_prep<<<5120, 256, 0, stream>>>(hid, hidA, Wq, Wk, Wv, Wp, WT);
  k_gemm_qkv<<<dim3(64, 24), 256, 0, stream>>>(hidA, WT, bq, bk, bv, QKV, VT);
  k_attn<<<dim3(64, 8), 256, 0, stream>>>(QKV, VT, CTX);
  k_gemm_proj<<<dim3(64, 8), 256, 0, stream>>>(CTX, WT + (size_t)3 * EMBED * EMBED, bp, hid, out,
                                               gamma, beta, CNT);
}

// Round 10
// 291.818 us; speedup vs baseline: 1.2769x; 1.2769x over previous
//
#include <hip/hip_runtime.h>

#define EMBED 1024
#define SEQ   2048
#define BATCH 4
#define HEADS 16

typedef __attribute__((ext_vector_type(8))) short short8;   // 8 bf16 in 4 VGPRs
typedef __attribute__((ext_vector_type(4))) float floatx4;
typedef __attribute__((ext_vector_type(16))) float floatx16;

#define MFMA16(a, b, c) __builtin_amdgcn_mfma_f32_16x16x32_bf16((a), (b), (c), 0, 0, 0)
#define MFMA32(a, b, c) __builtin_amdgcn_mfma_f32_32x32x16_bf16((a), (b), (c), 0, 0, 0)
#define ATT_SCALE (0.125f * 1.44269504088896340736f)   // 1/sqrt(64) * log2(e), folded into Q

static __device__ __forceinline__ unsigned short f2bf(float f) {
  union { float f; unsigned int u; } v; v.f = f;
  unsigned int u = v.u;
  u += 0x7fffu + ((u >> 16) & 1u);       // RNE
  return (unsigned short)(u >> 16);
}

// v_cvt_pk_bf16_f32: dst.lo16 = bf16(lo), dst.hi16 = bf16(hi)  (RNE)
static __device__ __forceinline__ unsigned cvtpk(float lo, float hi) {
  unsigned r;
  asm("v_cvt_pk_bf16_f32 %0, %1, %2" : "=v"(r) : "v"(lo), "v"(hi));
  return r;
}

static __device__ __forceinline__ void async16(const unsigned short* g, unsigned short* l) {
  __builtin_amdgcn_global_load_lds(
      (const __attribute__((address_space(1))) void*)g,
      (__attribute__((address_space(3))) void*)l, 16, 0, 0);
}

// ---------------- fused prep: hidden fp32->bf16 (blocks 0..4095) +
//                  W[k][n]->WT[n][k] bf16 for Wq,Wk,Wv,Wp (blocks 4096..5119) ---
__global__ __launch_bounds__(256) void k_prep(const float* __restrict__ hid,
                                              unsigned short* __restrict__ hidA,
                                              const float* __restrict__ Wq, const float* __restrict__ Wk,
                                              const float* __restrict__ Wv, const float* __restrict__ Wp,
                                              unsigned short* __restrict__ WT) {
  __shared__ unsigned short tile[64][65];
  const int bid = blockIdx.x, tid = threadIdx.x;
  if (bid < 4096) {                       // cvt: 8 floats / thread
    int i = bid * 256 + tid;
    const float4* s = (const float4*)hid;
    float4 a = s[i * 2], b = s[i * 2 + 1];
    uint4 o;
    o.x = (unsigned)f2bf(a.x) | ((unsigned)f2bf(a.y) << 16);
    o.y = (unsigned)f2bf(a.z) | ((unsigned)f2bf(a.w) << 16);
    o.z = (unsigned)f2bf(b.x) | ((unsigned)f2bf(b.y) << 16);
    o.w = (unsigned)f2bf(b.z) | ((unsigned)f2bf(b.w) << 16);
    ((uint4*)hidA)[i] = o;
    return;
  }
  const int idx = bid - 4096;
  const int z = idx >> 8, rem = idx & 255;
  const float* src = (z == 0) ? Wq : (z == 1) ? Wk : (z == 2) ? Wv : Wp;
  unsigned short* dst = WT + (size_t)z * EMBED * EMBED;
  const int k0 = (rem & 15) * 64, n0 = (rem >> 4) * 64;
  for (int i = tid; i < 4096; i += 256) {
    int r = i >> 6, c = i & 63;
    tile[c][r] = f2bf(src[(size_t)(k0 + r) * EMBED + n0 + c]);
  }
  __syncthreads();
  for (int i = tid; i < 4096; i += 256) {
    int r = i >> 6, c = i & 63;
    dst[(size_t)(n0 + r) * EMBED + k0 + c] = tile[r][c];
  }
}

// ---------------- QKV GEMM (128x128) + fused V-transpose, XCD-swizzled --------
// 1D grid 1536; bijective swizzle lb = (wg%8)*192 + wg/8 gives each XCD a
// contiguous run of 192 logical blocks = 3 B-panels (768 KB, L2-resident)
// instead of all 24 (T1).  Logical decode: by = lb/64, bx = lb%64.
// by < 16 : C[m][n0..] = hidA[m,:].WT_qk[n,:] + bias  (Q cols pre-scaled)
// by >= 16: V^T by operand symmetry (rows = d, cols = l); writes VT directly.
__global__ __launch_bounds__(256) void k_gemm_qkv(const unsigned short* __restrict__ A,
                                                  const unsigned short* __restrict__ BT,
                                                  const float* __restrict__ bq,
                                                  const float* __restrict__ bk,
                                                  const float* __restrict__ bv,
                                                  unsigned short* __restrict__ C,
                                                  unsigned short* __restrict__ VT) {
  __shared__ unsigned short Als[128 * 64];
  __shared__ unsigned short Bls[128 * 64];
  const int tid = threadIdx.x;
  const int wg = blockIdx.x;
  const int lb = (wg & 7) * 192 + (wg >> 3);    // 1536 = 8 * 192, bijective
  const int by = lb >> 6, bx = lb & 63;
  const bool vmode = (by >= 16);
  const int arow0 = vmode ? (by - 16) * 128 : bx * 128;
  const int brow0 = vmode ? bx * 128 : by * 128;
  const int w = tid >> 6, lane = tid & 63, l16 = lane & 15, quad = lane >> 4;
  const int l7 = l16 & 7;
  const int wrow = (w >> 1) * 64, wcol = (w & 1) * 64;

  floatx4 acc[4][4];
#pragma unroll
  for (int i = 0; i < 4; ++i)
#pragma unroll
    for (int j = 0; j < 4; ++j) acc[i][j] = {0.f, 0.f, 0.f, 0.f};

  const int srow = tid >> 3;
  const int scol = (((tid & 7) ^ (srow & 7)) * 8);
  const unsigned short* Arow = vmode ? (BT + (size_t)2 * EMBED * EMBED) : A;
  const unsigned short* Brow = vmode ? A : BT;
  const unsigned short* Ap = Arow + (size_t)(arow0 + srow) * EMBED + scol;
  const unsigned short* Bp = Brow + (size_t)(brow0 + srow) * EMBED + scol;

  int ab[2], bb[2];
#pragma unroll
  for (int kc = 0; kc < 2; ++kc) {
    ab[kc] = (wrow + l16) * 64 + (((4 * kc + quad) ^ l7) << 3);
    bb[kc] = (wcol + l16) * 64 + (((4 * kc + quad) ^ l7) << 3);
  }

  for (int kt = 0; kt < 16; ++kt) {
    const int k0 = kt * 64;
#pragma unroll
    for (int i = 0; i < 4; ++i)
      async16(Ap + k0 + (size_t)i * 32 * EMBED, Als + i * 2048 + tid * 8);
#pragma unroll
    for (int i = 0; i < 4; ++i)
      async16(Bp + k0 + (size_t)i * 32 * EMBED, Bls + i * 2048 + tid * 8);
    __syncthreads();
    short8 af[4][2], bf[4][2];
#pragma unroll
    for (int mt = 0; mt < 4; ++mt)
#pragma unroll
      for (int kc = 0; kc < 2; ++kc)
        af[mt][kc] = *(const short8*)(Als + ab[kc] + mt * 1024);
#pragma unroll
    for (int nt = 0; nt < 4; ++nt)
#pragma unroll
      for (int kc = 0; kc < 2; ++kc)
        bf[nt][kc] = *(const short8*)(Bls + bb[kc] + nt * 1024);
#pragma unroll
    for (int kc = 0; kc < 2; ++kc)
#pragma unroll
      for (int mt = 0; mt < 4; ++mt)
#pragma unroll
        for (int nt = 0; nt < 4; ++nt)
          acc[mt][nt] = MFMA16(af[mt][kc], bf[nt][kc], acc[mt][nt]);
    __syncthreads();
  }

  if (!vmode) {
    const int n0 = brow0;
    const float* bsel = (n0 < 1024) ? bq : bk;
    const float scl = (n0 < 1024) ? ATT_SCALE : 1.0f;
    const int nb = n0 & 1023;
    float bias[4];
#pragma unroll
    for (int nt = 0; nt < 4; ++nt) bias[nt] = bsel[nb + wcol + nt * 16 + l16];
#pragma unroll
    for (int mt = 0; mt < 4; ++mt)
#pragma unroll
      for (int r = 0; r < 4; ++r) {
        int gm = arow0 + wrow + mt * 16 + quad * 4 + r;
        size_t base = (size_t)gm * 3072 + n0 + wcol;
#pragma unroll
        for (int nt = 0; nt < 4; ++nt)
          C[base + nt * 16 + l16] = f2bf((acc[mt][nt][r] + bias[nt]) * scl);
      }
  } else {
    // rows = d-global, cols = l-global; VT[(b*16+h)*64 + d][l]
#pragma unroll
    for (int mt = 0; mt < 4; ++mt)
#pragma unroll
      for (int r = 0; r < 4; ++r) {
        const int drow = arow0 + wrow + mt * 16 + quad * 4 + r;   // 0..1023
        const float bias = bv[drow];
        const int cg0 = brow0 + wcol;                             // col base (l-global)
        const int b = cg0 >> 11;                                  // constant per block
        const size_t base = ((size_t)((b * 16 + (drow >> 6)) * 64 + (drow & 63))) * SEQ
                            + (cg0 & 2047);
#pragma unroll
        for (int nt = 0; nt < 4; ++nt)
          VT[base + nt * 16 + l16] = f2bf(acc[mt][nt][r] + bias);
      }
  }
}

// QK step: S[kvg][qg] = K-tile(LDS) x Q(frags), swapped-operand 32x32
static __device__ __forceinline__ void qk_step(const unsigned short* Kc,
                                               const short8 qf[2][4],
                                               int l32, int hi,
                                               floatx16 S[2][2]) {
#pragma unroll
  for (int kvg = 0; kvg < 2; ++kvg) {
    short8 kf[4];
#pragma unroll
    for (int ds = 0; ds < 4; ++ds) {
      const int row = kvg * 32 + l32;
      kf[ds] = *(const short8*)(Kc + row * 64 + (((ds * 2 + hi) ^ (row & 7)) << 3));
    }
#pragma unroll
    for (int qg = 0; qg < 2; ++qg) {
      floatx16 s;
#pragma unroll
      for (int c = 0; c < 16; ++c) s[c] = 0.f;
#pragma unroll
      for (int ds = 0; ds < 4; ++ds) s = MFMA32(kf[ds], qf[qg][ds], s);
      S[kvg][qg] = s;
    }
  }
}

// ---------------- attention v14: v10 + software-pipelined S (T15) -------------
// Iteration kt: exp2/pack(S of tile kt) -> PV(tile kt) -> QK(tile kt+1 -> S).
// K staged TWO ahead (K[kt+2]->Kls[kt&1]), V one ahead (V[kt+1]->Vls[(kt+1)&1]).
// Per-tile math order unchanged -> bit-identical output.
__global__ __launch_bounds__(256, 2) void k_attn(const unsigned short* __restrict__ QKV,
                                                 const unsigned short* __restrict__ VT,
                                                 unsigned short* __restrict__ CTX) {
  const int bh = blockIdx.x, qt = blockIdx.y;
  const int b = bh >> 4, h = bh & 15;
  const int tid = threadIdx.x;
  const int w = tid >> 6, lane = tid & 63;
  const int l32 = lane & 31, hi = lane >> 5;

  __shared__ unsigned short Kls[2][64 * 64];   // [buf][kv][d]  xor-chunk swizzled
  __shared__ unsigned short Vls[2][64 * 64];   // [buf][d][kv]  xor-chunk swizzled
  __shared__ float rsls[4][64];                // per-wave row sums

  const unsigned short* Qb = QKV + (size_t)(b * SEQ + qt * 256 + w * 64) * 3072 + h * 64;
  const unsigned short* Kb = QKV + (size_t)(b * SEQ) * 3072 + 1024 + h * 64;
  const unsigned short* Vb = VT + (size_t)bh * 64 * SEQ;

  // Q fragments (B-operand of swapped QK): qf[qg][ds] holds
  // Q[q = qg*32 + l32][d = ds*16 + hi*8 + j]  (pre-scaled by ATT_SCALE)
  short8 qf[2][4];
#pragma unroll
  for (int qg = 0; qg < 2; ++qg)
#pragma unroll
    for (int ds = 0; ds < 4; ++ds)
      qf[qg][ds] = *(const short8*)(Qb + (size_t)(qg * 32 + l32) * 3072 + ds * 16 + hi * 8);

  floatx16 o[2][2];
  floatx16 S[2][2];
  float rs[2] = {0.f, 0.f};
#pragma unroll
  for (int qg = 0; qg < 2; ++qg)
#pragma unroll
    for (int dg = 0; dg < 2; ++dg)
#pragma unroll
      for (int c = 0; c < 16; ++c) o[qg][dg][c] = 0.f;

  const int srow = tid >> 3;                              // 0..31
  const int scol = (((tid & 7) ^ (srow & 7)) * 8);        // swizzled source chunk

  // prologue: stage K[0],V[0] -> buf0, K[1] -> buf1
  async16(Kb + (size_t)srow * 3072 + scol, Kls[0] + tid * 8);
  async16(Kb + (size_t)(32 + srow) * 3072 + scol, Kls[0] + 2048 + tid * 8);
  async16(Vb + (size_t)srow * SEQ + scol, Vls[0] + tid * 8);
  async16(Vb + (size_t)(32 + srow) * SEQ + scol, Vls[0] + 2048 + tid * 8);
  async16(Kb + (size_t)(64 + srow) * 3072 + scol, Kls[1] + tid * 8);
  async16(Kb + (size_t)(64 + 32 + srow) * 3072 + scol, Kls[1] + 2048 + tid * 8);
  __syncthreads();

  // QK tile 0 -> S (reads Kls[0])
  qk_step(Kls[0], qf, l32, hi, S);
  __syncthreads();   // all waves done with Kls[0] before kt=0 stages K[2] there

  for (int kt = 0; kt < 32; ++kt) {
    const int cur = kt & 1;
    // stage V[kt+1] -> Vls[cur^1]  (PV this iter reads Vls[cur])
    if (kt < 31) {
      const int vn = (kt + 1) * 64;
      unsigned short* Vd = Vls[cur ^ 1];
      async16(Vb + (size_t)srow * SEQ + vn + scol, Vd + tid * 8);
      async16(Vb + (size_t)(32 + srow) * SEQ + vn + scol, Vd + 2048 + tid * 8);
    }
    // stage K[kt+2] -> Kls[cur]  (QK this iter reads Kls[cur^1])
    if (kt < 30) {
      const int kn = (kt + 2) * 64;
      unsigned short* Kd = Kls[cur];
      async16(Kb + (size_t)(kn + srow) * 3072 + scol, Kd + tid * 8);
      async16(Kb + (size_t)(kn + 32 + srow) * 3072 + scol, Kd + 2048 + tid * 8);
    }

    // exp2 + pack of tile kt (reads S; independent of this iter's QK below)
    short8 pa[2][4];   // [qg][ks] packed P fragments (PV A-operand)
#pragma unroll
    for (int kvg = 0; kvg < 2; ++kvg)
#pragma unroll
      for (int qg = 0; qg < 2; ++qg) {
        float p[16];
#pragma unroll
        for (int c = 0; c < 16; ++c) p[c] = __builtin_amdgcn_exp2f(S[kvg][qg][c]);
        rs[qg] += (((p[0] + p[1]) + (p[2] + p[3])) + ((p[4] + p[5]) + (p[6] + p[7])))
                + (((p[8] + p[9]) + (p[10] + p[11])) + ((p[12] + p[13]) + (p[14] + p[15])));
#pragma unroll
        for (int half = 0; half < 2; ++half) {   // ks = kvg*2 + half
          unsigned w0 = cvtpk(p[half * 8 + 0], p[half * 8 + 1]);
          unsigned w1 = cvtpk(p[half * 8 + 2], p[half * 8 + 3]);
          unsigned w2 = cvtpk(p[half * 8 + 4], p[half * 8 + 5]);
          unsigned w3 = cvtpk(p[half * 8 + 6], p[half * 8 + 7]);
          asm("v_permlane32_swap_b32 %0, %1" : "+v"(w0), "+v"(w2));
          asm("v_permlane32_swap_b32 %0, %1" : "+v"(w1), "+v"(w3));
          union { unsigned u[4]; short8 s8; } pk;
          pk.u[0] = w0; pk.u[1] = w1; pk.u[2] = w2; pk.u[3] = w3;
          pa[qg][kvg * 2 + half] = pk.s8;
        }
      }

    // O += P V   (V[kt] in Vls[cur])
#pragma unroll
    for (int dg = 0; dg < 2; ++dg) {
      short8 vf[4];
#pragma unroll
      for (int ks = 0; ks < 4; ++ks) {
        const int row = dg * 32 + l32;
        vf[ks] = *(const short8*)(Vls[cur] + row * 64 + (((ks * 2 + hi) ^ (row & 7)) << 3));
      }
#pragma unroll
      for (int qg = 0; qg < 2; ++qg)
#pragma unroll
        for (int ks = 0; ks < 4; ++ks)
          o[qg][dg] = MFMA32(pa[qg][ks], vf[ks], o[qg][dg]);
    }

    // QK tile kt+1 -> S  (K[kt+1] in Kls[cur^1]; overlaps pack/PV above)
    if (kt < 31) qk_step(Kls[cur ^ 1], qf, l32, hi, S);

    // single barrier: drains this iter's stages and protects staged buffers
    __syncthreads();
  }

  // lanes l and l+32 hold the same q; combine, publish per-q sums via LDS
  rs[0] += __shfl_xor(rs[0], 32);
  rs[1] += __shfl_xor(rs[1], 32);
  if (lane < 32) {
    rsls[w][l32] = rs[0];
    rsls[w][32 + l32] = rs[1];
  }
  // same-wave LDS readback; per-wave in-order, compiler inserts the lgkm wait

  // write ctx[b*SEQ + q][h*64 + d] bf16; O rows: q = (j&3)+8*(j>>2)+4*hi (+32qg)
#pragma unroll
  for (int qg = 0; qg < 2; ++qg)
#pragma unroll
    for (int j = 0; j < 16; ++j) {
      const int rl = (j & 3) + 8 * (j >> 2) + 4 * hi;
      const float inv = 1.f / rsls[w][qg * 32 + rl];
      const int gq = b * SEQ + qt * 256 + w * 64 + qg * 32 + rl;
      const size_t base = (size_t)gq * EMBED + h * 64;
#pragma unroll
      for (int dg = 0; dg < 2; ++dg)
        CTX[base + dg * 32 + l32] = f2bf(o[qg][dg][j] * inv);
    }
}

// ---------------- proj GEMM + bias + residual -> fp32 x, XCD-swizzled ---------
// 1D grid 512; lb = (wg%8)*64 + wg/8: each XCD owns ONE n-panel (n0 = lb/64),
// all 64 m-bands — the Wp B-panel (256 KB) stays L2-resident per XCD (T1).
// R9 lesson: do NOT fuse LN here — device-scope fences on 8 non-coherent L2s
// cost ~110us; a kernel boundary is the cheap synchronization.
__global__ __launch_bounds__(256) void k_gemm_proj(const unsigned short* __restrict__ A,
                                                   const unsigned short* __restrict__ BT,
                                                   const float* __restrict__ bp,
                                                   const float* __restrict__ hid,
                                                   float* __restrict__ X) {
  __shared__ unsigned short Als[128 * 64];
  __shared__ unsigned short Bls[128 * 64];
  const int tid = threadIdx.x;
  const int wg = blockIdx.x;
  const int lb = (wg & 7) * 64 + (wg >> 3);     // 512 = 8 * 64, bijective
  const int m0 = (lb & 63) * 128, n0 = (lb >> 6) * 128;
  const int w = tid >> 6, lane = tid & 63, l16 = lane & 15, quad = lane >> 4;
  const int l7 = l16 & 7;
  const int wrow = (w >> 1) * 64, wcol = (w & 1) * 64;

  floatx4 acc[4][4];
#pragma unroll
  for (int i = 0; i < 4; ++i)
#pragma unroll
    for (int j = 0; j < 4; ++j) acc[i][j] = {0.f, 0.f, 0.f, 0.f};

  const int srow = tid >> 3;
  const int scol = (((tid & 7) ^ (srow & 7)) * 8);
  const unsigned short* Ap = A + (size_t)(m0 + srow) * EMBED + scol;
  const unsigned short* Bp = BT + (size_t)(n0 + srow) * EMBED + scol;

  int ab[2], bb[2];
#pragma unroll
  for (int kc = 0; kc < 2; ++kc) {
    ab[kc] = (wrow + l16) * 64 + (((4 * kc + quad) ^ l7) << 3);
    bb[kc] = (wcol + l16) * 64 + (((4 * kc + quad) ^ l7) << 3);
  }

  for (int kt = 0; kt < 16; ++kt) {
    const int k0 = kt * 64;
#pragma unroll
    for (int i = 0; i < 4; ++i)
      async16(Ap + k0 + (size_t)i * 32 * EMBED, Als + i * 2048 + tid * 8);
#pragma unroll
    for (int i = 0; i < 4; ++i)
      async16(Bp + k0 + (size_t)i * 32 * EMBED, Bls + i * 2048 + tid * 8);
    __syncthreads();
    short8 af[4][2], bf[4][2];
#pragma unroll
    for (int mt = 0; mt < 4; ++mt)
#pragma unroll
      for (int kc = 0; kc < 2; ++kc)
        af[mt][kc] = *(const short8*)(Als + ab[kc] + mt * 1024);
#pragma unroll
    for (int nt = 0; nt < 4; ++nt)
#pragma unroll
      for (int kc = 0; kc < 2; ++kc)
        bf[nt][kc] = *(const short8*)(Bls + bb[kc] + nt * 1024);
#pragma unroll
    for (int kc = 0; kc < 2; ++kc)
#pragma unroll
      for (int mt = 0; mt < 4; ++mt)
#pragma unroll
        for (int nt = 0; nt < 4; ++nt)
          acc[mt][nt] = MFMA16(af[mt][kc], bf[nt][kc], acc[mt][nt]);
    __syncthreads();
  }

  float bias[4];
#pragma unroll
  for (int nt = 0; nt < 4; ++nt) bias[nt] = bp[n0 + wcol + nt * 16 + l16];
#pragma unroll
  for (int mt = 0; mt < 4; ++mt)
#pragma unroll
    for (int r = 0; r < 4; ++r) {
      int gm = m0 + wrow + mt * 16 + quad * 4 + r;
      size_t base = (size_t)gm * EMBED + n0 + wcol;
#pragma unroll
      for (int nt = 0; nt < 4; ++nt) {
        size_t idx = base + nt * 16 + l16;
        X[idx] = acc[mt][nt][r] + bias[nt] + hid[idx];
      }
    }
}

// ---------------- in-place LayerNorm over E=1024, one block per row ----------------
__global__ __launch_bounds__(256) void k_ln(float* __restrict__ x,
                                            const float* __restrict__ gamma,
                                            const float* __restrict__ beta) {
  int row = blockIdx.x, tid = threadIdx.x;
  float4* rp = (float4*)(x + (size_t)row * EMBED);
  float4 v = rp[tid];
  float s = v.x + v.y + v.z + v.w;
  float q = v.x * v.x + v.y * v.y + v.z * v.z + v.w * v.w;
#pragma unroll
  for (int off = 1; off < 64; off <<= 1) {
    s += __shfl_xor(s, off);
    q += __shfl_xor(q, off);
  }
  __shared__ float ss[4], sq[4];
  int w = tid >> 6;
  if ((tid & 63) == 0) { ss[w] = s; sq[w] = q; }
  __syncthreads();
  s = ss[0] + ss[1] + ss[2] + ss[3];
  q = sq[0] + sq[1] + sq[2] + sq[3];
  float mean = s * (1.f / 1024.f);
  float var = q * (1.f / 1024.f) - mean * mean;
  float rstd = rsqrtf(var + 1e-8f);
  float4 g = ((const float4*)gamma)[tid];
  float4 be = ((const float4*)beta)[tid];
  v.x = (v.x - mean) * rstd * g.x + be.x;
  v.y = (v.y - mean) * rstd * g.y + be.y;
  v.z = (v.z - mean) * rstd * g.z + be.z;
  v.w = (v.w - mean) * rstd * g.w + be.w;
  rp[tid] = v;
}

extern "C" void kernel_launch(void* const* d_in, const int* in_sizes, int n_in,
                              void* d_out, int out_size, void* d_ws, size_t ws_size,
                              hipStream_t stream) {
  const float* hid   = (const float*)d_in[0];
  const float* Wq    = (const float*)d_in[1];
  const float* bq    = (const float*)d_in[2];
  const float* Wk    = (const float*)d_in[3];
  const float* bk    = (const float*)d_in[4];
  const float* Wv    = (const float*)d_in[5];
  const float* bv    = (const float*)d_in[6];
  const float* Wp    = (const float*)d_in[7];
  const float* bp    = (const float*)d_in[8];
  const float* gamma = (const float*)d_in[9];
  const float* beta  = (const float*)d_in[10];
  float* out = (float*)d_out;

  char* ws = (char*)d_ws;
  unsigned short* hidA = (unsigned short*)ws;                          // 16 MB  [8192][1024]
  unsigned short* WT   = (unsigned short*)(ws + (size_t)(16 << 20));   //  8 MB  [4096][1024]
  unsigned short* QKV  = (unsigned short*)(ws + (size_t)(24 << 20));   // 48 MB  [8192][3072] (V third unused)
  unsigned short* VT   = (unsigned short*)(ws + (size_t)(72 << 20));   // 16 MB  [64][64][2048]
  unsigned short* CTX  = (unsigned short*)(ws + (size_t)(88 << 20));   // 16 MB  [8192][1024]

  k_prep<<<5120, 256, 0, stream>>>(hid, hidA, Wq, Wk, Wv, Wp, WT);
  k_gemm_qkv<<<1536, 256, 0, stream>>>(hidA, WT, bq, bk, bv, QKV, VT);
  k_attn<<<dim3(64, 8), 256, 0, stream>>>(QKV, VT, CTX);
  k_gemm_proj<<<512, 256, 0, stream>>>(CTX, WT + (size_t)3 * EMBED * EMBED, bp, hid, out);
  k_ln<<<8192, 256, 0, stream>>>(out, gamma, beta);
}

// Round 11
// 282.241 us; speedup vs baseline: 1.3202x; 1.0339x over previous
//
#include <hip/hip_runtime.h>

#define EMBED 1024
#define SEQ   2048
#define BATCH 4
#define HEADS 16

typedef __attribute__((ext_vector_type(8))) short short8;   // 8 bf16 in 4 VGPRs
typedef __attribute__((ext_vector_type(4))) float floatx4;
typedef __attribute__((ext_vector_type(16))) float floatx16;

#define MFMA16(a, b, c) __builtin_amdgcn_mfma_f32_16x16x32_bf16((a), (b), (c), 0, 0, 0)
#define MFMA32(a, b, c) __builtin_amdgcn_mfma_f32_32x32x16_bf16((a), (b), (c), 0, 0, 0)
#define ATT_SCALE (0.125f * 1.44269504088896340736f)   // 1/sqrt(64) * log2(e), folded into Q

static __device__ __forceinline__ unsigned short f2bf(float f) {
  union { float f; unsigned int u; } v; v.f = f;
  unsigned int u = v.u;
  u += 0x7fffu + ((u >> 16) & 1u);       // RNE
  return (unsigned short)(u >> 16);
}

// v_cvt_pk_bf16_f32: dst.lo16 = bf16(lo), dst.hi16 = bf16(hi)  (RNE)
static __device__ __forceinline__ unsigned cvtpk(float lo, float hi) {
  unsigned r;
  asm("v_cvt_pk_bf16_f32 %0, %1, %2" : "=v"(r) : "v"(lo), "v"(hi));
  return r;
}

static __device__ __forceinline__ void async16(const unsigned short* g, unsigned short* l) {
  __builtin_amdgcn_global_load_lds(
      (const __attribute__((address_space(1))) void*)g,
      (__attribute__((address_space(3))) void*)l, 16, 0, 0);
}

// ---------------- fused prep: hidden fp32->bf16 (blocks 0..4095) +
//                  W[k][n]->WT[n][k] bf16 for Wq,Wk,Wv,Wp (blocks 4096..5119) ---
__global__ __launch_bounds__(256) void k_prep(const float* __restrict__ hid,
                                              unsigned short* __restrict__ hidA,
                                              const float* __restrict__ Wq, const float* __restrict__ Wk,
                                              const float* __restrict__ Wv, const float* __restrict__ Wp,
                                              unsigned short* __restrict__ WT) {
  __shared__ unsigned short tile[64][65];
  const int bid = blockIdx.x, tid = threadIdx.x;
  if (bid < 4096) {                       // cvt: 8 floats / thread
    int i = bid * 256 + tid;
    const float4* s = (const float4*)hid;
    float4 a = s[i * 2], b = s[i * 2 + 1];
    uint4 o;
    o.x = (unsigned)f2bf(a.x) | ((unsigned)f2bf(a.y) << 16);
    o.y = (unsigned)f2bf(a.z) | ((unsigned)f2bf(a.w) << 16);
    o.z = (unsigned)f2bf(b.x) | ((unsigned)f2bf(b.y) << 16);
    o.w = (unsigned)f2bf(b.z) | ((unsigned)f2bf(b.w) << 16);
    ((uint4*)hidA)[i] = o;
    return;
  }
  const int idx = bid - 4096;
  const int z = idx >> 8, rem = idx & 255;
  const float* src = (z == 0) ? Wq : (z == 1) ? Wk : (z == 2) ? Wv : Wp;
  unsigned short* dst = WT + (size_t)z * EMBED * EMBED;
  const int k0 = (rem & 15) * 64, n0 = (rem >> 4) * 64;
  for (int i = tid; i < 4096; i += 256) {
    int r = i >> 6, c = i & 63;
    tile[c][r] = f2bf(src[(size_t)(k0 + r) * EMBED + n0 + c]);
  }
  __syncthreads();
  for (int i = tid; i < 4096; i += 256) {
    int r = i >> 6, c = i & 63;
    dst[(size_t)(n0 + r) * EMBED + k0 + c] = tile[r][c];
  }
}

// ---------------- QKV GEMM (128x128, proven structure) + fused V-transpose ----
// by < 16 : C[m][n0..] = hidA[m,:].WT_qk[n,:] + bias  (Q cols pre-scaled)
// by >= 16: V^T by operand symmetry (rows = d, cols = l); writes VT directly.
// R10 lesson: default 2D dispatch already time-correlates same-panel blocks
// across XCDs (L3 absorbs panel re-reads); per-XCD panel swizzle de-correlated
// the A streams and quadrupled FETCH.  Keep the natural grid.
__global__ __launch_bounds__(256) void k_gemm_qkv(const unsigned short* __restrict__ A,
                                                  const unsigned short* __restrict__ BT,
                                                  const float* __restrict__ bq,
                                                  const float* __restrict__ bk,
                                                  const float* __restrict__ bv,
                                                  unsigned short* __restrict__ C,
                                                  unsigned short* __restrict__ VT) {
  __shared__ unsigned short Als[128 * 64];
  __shared__ unsigned short Bls[128 * 64];
  const int tid = threadIdx.x;
  const int by = blockIdx.y;
  const bool vmode = (by >= 16);
  const int arow0 = vmode ? (by - 16) * 128 : blockIdx.x * 128;
  const int brow0 = vmode ? blockIdx.x * 128 : by * 128;
  const int w = tid >> 6, lane = tid & 63, l16 = lane & 15, quad = lane >> 4;
  const int l7 = l16 & 7;
  const int wrow = (w >> 1) * 64, wcol = (w & 1) * 64;

  floatx4 acc[4][4];
#pragma unroll
  for (int i = 0; i < 4; ++i)
#pragma unroll
    for (int j = 0; j < 4; ++j) acc[i][j] = {0.f, 0.f, 0.f, 0.f};

  const int srow = tid >> 3;
  const int scol = (((tid & 7) ^ (srow & 7)) * 8);
  const unsigned short* Arow = vmode ? (BT + (size_t)2 * EMBED * EMBED) : A;
  const unsigned short* Brow = vmode ? A : BT;
  const unsigned short* Ap = Arow + (size_t)(arow0 + srow) * EMBED + scol;
  const unsigned short* Bp = Brow + (size_t)(brow0 + srow) * EMBED + scol;

  int ab[2], bb[2];
#pragma unroll
  for (int kc = 0; kc < 2; ++kc) {
    ab[kc] = (wrow + l16) * 64 + (((4 * kc + quad) ^ l7) << 3);
    bb[kc] = (wcol + l16) * 64 + (((4 * kc + quad) ^ l7) << 3);
  }

  for (int kt = 0; kt < 16; ++kt) {
    const int k0 = kt * 64;
#pragma unroll
    for (int i = 0; i < 4; ++i)
      async16(Ap + k0 + (size_t)i * 32 * EMBED, Als + i * 2048 + tid * 8);
#pragma unroll
    for (int i = 0; i < 4; ++i)
      async16(Bp + k0 + (size_t)i * 32 * EMBED, Bls + i * 2048 + tid * 8);
    __syncthreads();
    short8 af[4][2], bf[4][2];
#pragma unroll
    for (int mt = 0; mt < 4; ++mt)
#pragma unroll
      for (int kc = 0; kc < 2; ++kc)
        af[mt][kc] = *(const short8*)(Als + ab[kc] + mt * 1024);
#pragma unroll
    for (int nt = 0; nt < 4; ++nt)
#pragma unroll
      for (int kc = 0; kc < 2; ++kc)
        bf[nt][kc] = *(const short8*)(Bls + bb[kc] + nt * 1024);
#pragma unroll
    for (int kc = 0; kc < 2; ++kc)
#pragma unroll
      for (int mt = 0; mt < 4; ++mt)
#pragma unroll
        for (int nt = 0; nt < 4; ++nt)
          acc[mt][nt] = MFMA16(af[mt][kc], bf[nt][kc], acc[mt][nt]);
    __syncthreads();
  }

  if (!vmode) {
    const int n0 = brow0;
    const float* bsel = (n0 < 1024) ? bq : bk;
    const float scl = (n0 < 1024) ? ATT_SCALE : 1.0f;
    const int nb = n0 & 1023;
    float bias[4];
#pragma unroll
    for (int nt = 0; nt < 4; ++nt) bias[nt] = bsel[nb + wcol + nt * 16 + l16];
#pragma unroll
    for (int mt = 0; mt < 4; ++mt)
#pragma unroll
      for (int r = 0; r < 4; ++r) {
        int gm = arow0 + wrow + mt * 16 + quad * 4 + r;
        size_t base = (size_t)gm * 3072 + n0 + wcol;
#pragma unroll
        for (int nt = 0; nt < 4; ++nt)
          C[base + nt * 16 + l16] = f2bf((acc[mt][nt][r] + bias[nt]) * scl);
      }
  } else {
    // rows = d-global, cols = l-global; VT[(b*16+h)*64 + d][l]
#pragma unroll
    for (int mt = 0; mt < 4; ++mt)
#pragma unroll
      for (int r = 0; r < 4; ++r) {
        const int drow = arow0 + wrow + mt * 16 + quad * 4 + r;   // 0..1023
        const float bias = bv[drow];
        const int cg0 = brow0 + wcol;                             // col base (l-global)
        const int b = cg0 >> 11;                                  // constant per block
        const size_t base = ((size_t)((b * 16 + (drow >> 6)) * 64 + (drow & 63))) * SEQ
                            + (cg0 & 2047);
#pragma unroll
        for (int nt = 0; nt < 4; ++nt)
          VT[base + nt * 16 + l16] = f2bf(acc[mt][nt][r] + bias);
      }
  }
}

// QK step: S[kvg][qg] = K-tile(LDS) x Q(frags), swapped-operand 32x32
static __device__ __forceinline__ void qk_step(const unsigned short* Kc,
                                               const short8 qf[2][4],
                                               int l32, int hi,
                                               floatx16 S[2][2]) {
#pragma unroll
  for (int kvg = 0; kvg < 2; ++kvg) {
    short8 kf[4];
#pragma unroll
    for (int ds = 0; ds < 4; ++ds) {
      const int row = kvg * 32 + l32;
      kf[ds] = *(const short8*)(Kc + row * 64 + (((ds * 2 + hi) ^ (row & 7)) << 3));
    }
#pragma unroll
    for (int qg = 0; qg < 2; ++qg) {
      floatx16 s;
#pragma unroll
      for (int c = 0; c < 16; ++c) s[c] = 0.f;
#pragma unroll
      for (int ds = 0; ds < 4; ++ds) s = MFMA32(kf[ds], qf[qg][ds], s);
      S[kvg][qg] = s;
    }
  }
}

// ---------------- attention v15: v14 + setprio on the MFMA region (T5) --------
// Iteration kt: exp2/pack(S of tile kt) -> PV(tile kt) -> QK(tile kt+1 -> S).
// K staged TWO ahead (K[kt+2]->Kls[kt&1]), V one ahead (V[kt+1]->Vls[(kt+1)&1]).
// 2 blocks/CU at independent phases -> setprio's measured-positive regime.
// Per-tile math order unchanged -> bit-identical output.
__global__ __launch_bounds__(256, 2) void k_attn(const unsigned short* __restrict__ QKV,
                                                 const unsigned short* __restrict__ VT,
                                                 unsigned short* __restrict__ CTX) {
  const int bh = blockIdx.x, qt = blockIdx.y;
  const int b = bh >> 4, h = bh & 15;
  const int tid = threadIdx.x;
  const int w = tid >> 6, lane = tid & 63;
  const int l32 = lane & 31, hi = lane >> 5;

  __shared__ unsigned short Kls[2][64 * 64];   // [buf][kv][d]  xor-chunk swizzled
  __shared__ unsigned short Vls[2][64 * 64];   // [buf][d][kv]  xor-chunk swizzled
  __shared__ float rsls[4][64];                // per-wave row sums

  const unsigned short* Qb = QKV + (size_t)(b * SEQ + qt * 256 + w * 64) * 3072 + h * 64;
  const unsigned short* Kb = QKV + (size_t)(b * SEQ) * 3072 + 1024 + h * 64;
  const unsigned short* Vb = VT + (size_t)bh * 64 * SEQ;

  // Q fragments (B-operand of swapped QK): qf[qg][ds] holds
  // Q[q = qg*32 + l32][d = ds*16 + hi*8 + j]  (pre-scaled by ATT_SCALE)
  short8 qf[2][4];
#pragma unroll
  for (int qg = 0; qg < 2; ++qg)
#pragma unroll
    for (int ds = 0; ds < 4; ++ds)
      qf[qg][ds] = *(const short8*)(Qb + (size_t)(qg * 32 + l32) * 3072 + ds * 16 + hi * 8);

  floatx16 o[2][2];
  floatx16 S[2][2];
  float rs[2] = {0.f, 0.f};
#pragma unroll
  for (int qg = 0; qg < 2; ++qg)
#pragma unroll
    for (int dg = 0; dg < 2; ++dg)
#pragma unroll
      for (int c = 0; c < 16; ++c) o[qg][dg][c] = 0.f;

  const int srow = tid >> 3;                              // 0..31
  const int scol = (((tid & 7) ^ (srow & 7)) * 8);        // swizzled source chunk

  // prologue: stage K[0],V[0] -> buf0, K[1] -> buf1
  async16(Kb + (size_t)srow * 3072 + scol, Kls[0] + tid * 8);
  async16(Kb + (size_t)(32 + srow) * 3072 + scol, Kls[0] + 2048 + tid * 8);
  async16(Vb + (size_t)srow * SEQ + scol, Vls[0] + tid * 8);
  async16(Vb + (size_t)(32 + srow) * SEQ + scol, Vls[0] + 2048 + tid * 8);
  async16(Kb + (size_t)(64 + srow) * 3072 + scol, Kls[1] + tid * 8);
  async16(Kb + (size_t)(64 + 32 + srow) * 3072 + scol, Kls[1] + 2048 + tid * 8);
  __syncthreads();

  // QK tile 0 -> S (reads Kls[0])
  qk_step(Kls[0], qf, l32, hi, S);
  __syncthreads();   // all waves done with Kls[0] before kt=0 stages K[2] there

  for (int kt = 0; kt < 32; ++kt) {
    const int cur = kt & 1;
    // stage V[kt+1] -> Vls[cur^1]  (PV this iter reads Vls[cur])
    if (kt < 31) {
      const int vn = (kt + 1) * 64;
      unsigned short* Vd = Vls[cur ^ 1];
      async16(Vb + (size_t)srow * SEQ + vn + scol, Vd + tid * 8);
      async16(Vb + (size_t)(32 + srow) * SEQ + vn + scol, Vd + 2048 + tid * 8);
    }
    // stage K[kt+2] -> Kls[cur]  (QK this iter reads Kls[cur^1])
    if (kt < 30) {
      const int kn = (kt + 2) * 64;
      unsigned short* Kd = Kls[cur];
      async16(Kb + (size_t)(kn + srow) * 3072 + scol, Kd + tid * 8);
      async16(Kb + (size_t)(kn + 32 + srow) * 3072 + scol, Kd + 2048 + tid * 8);
    }

    // exp2 + pack of tile kt (reads S; independent of this iter's QK below)
    short8 pa[2][4];   // [qg][ks] packed P fragments (PV A-operand)
#pragma unroll
    for (int kvg = 0; kvg < 2; ++kvg)
#pragma unroll
      for (int qg = 0; qg < 2; ++qg) {
        float p[16];
#pragma unroll
        for (int c = 0; c < 16; ++c) p[c] = __builtin_amdgcn_exp2f(S[kvg][qg][c]);
        rs[qg] += (((p[0] + p[1]) + (p[2] + p[3])) + ((p[4] + p[5]) + (p[6] + p[7])))
                + (((p[8] + p[9]) + (p[10] + p[11])) + ((p[12] + p[13]) + (p[14] + p[15])));
#pragma unroll
        for (int half = 0; half < 2; ++half) {   // ks = kvg*2 + half
          unsigned w0 = cvtpk(p[half * 8 + 0], p[half * 8 + 1]);
          unsigned w1 = cvtpk(p[half * 8 + 2], p[half * 8 + 3]);
          unsigned w2 = cvtpk(p[half * 8 + 4], p[half * 8 + 5]);
          unsigned w3 = cvtpk(p[half * 8 + 6], p[half * 8 + 7]);
          asm("v_permlane32_swap_b32 %0, %1" : "+v"(w0), "+v"(w2));
          asm("v_permlane32_swap_b32 %0, %1" : "+v"(w1), "+v"(w3));
          union { unsigned u[4]; short8 s8; } pk;
          pk.u[0] = w0; pk.u[1] = w1; pk.u[2] = w2; pk.u[3] = w3;
          pa[qg][kvg * 2 + half] = pk.s8;
        }
      }

    // O += P V   (V[kt] in Vls[cur]) — MFMA-dense region gets priority (T5)
    __builtin_amdgcn_s_setprio(1);
#pragma unroll
    for (int dg = 0; dg < 2; ++dg) {
      short8 vf[4];
#pragma unroll
      for (int ks = 0; ks < 4; ++ks) {
        const int row = dg * 32 + l32;
        vf[ks] = *(const short8*)(Vls[cur] + row * 64 + (((ks * 2 + hi) ^ (row & 7)) << 3));
      }
#pragma unroll
      for (int qg = 0; qg < 2; ++qg)
#pragma unroll
        for (int ks = 0; ks < 4; ++ks)
          o[qg][dg] = MFMA32(pa[qg][ks], vf[ks], o[qg][dg]);
    }

    // QK tile kt+1 -> S  (K[kt+1] in Kls[cur^1]; overlaps pack/PV above)
    if (kt < 31) qk_step(Kls[cur ^ 1], qf, l32, hi, S);
    __builtin_amdgcn_s_setprio(0);

    // single barrier: drains this iter's stages and protects staged buffers
    __syncthreads();
  }

  // lanes l and l+32 hold the same q; combine, publish per-q sums via LDS
  rs[0] += __shfl_xor(rs[0], 32);
  rs[1] += __shfl_xor(rs[1], 32);
  if (lane < 32) {
    rsls[w][l32] = rs[0];
    rsls[w][32 + l32] = rs[1];
  }
  // same-wave LDS readback; per-wave in-order, compiler inserts the lgkm wait

  // write ctx[b*SEQ + q][h*64 + d] bf16; O rows: q = (j&3)+8*(j>>2)+4*hi (+32qg)
#pragma unroll
  for (int qg = 0; qg < 2; ++qg)
#pragma unroll
    for (int j = 0; j < 16; ++j) {
      const int rl = (j & 3) + 8 * (j >> 2) + 4 * hi;
      const float inv = 1.f / rsls[w][qg * 32 + rl];
      const int gq = b * SEQ + qt * 256 + w * 64 + qg * 32 + rl;
      const size_t base = (size_t)gq * EMBED + h * 64;
#pragma unroll
      for (int dg = 0; dg < 2; ++dg)
        CTX[base + dg * 32 + l32] = f2bf(o[qg][dg][j] * inv);
    }
}

// ---------------- proj GEMM + bias + residual -> fp32 x ----------------
// R9 lesson: no in-kernel LN fusion (device fences on 8 non-coherent L2s cost
// ~110us); R10 lesson: no XCD swizzle (default dispatch already L3-friendly).
__global__ __launch_bounds__(256) void k_gemm_proj(const unsigned short* __restrict__ A,
                                                   const unsigned short* __restrict__ BT,
                                                   const float* __restrict__ bp,
                                                   const float* __restrict__ hid,
                                                   float* __restrict__ X) {
  __shared__ unsigned short Als[128 * 64];
  __shared__ unsigned short Bls[128 * 64];
  const int tid = threadIdx.x;
  const int m0 = blockIdx.x * 128, n0 = blockIdx.y * 128;
  const int w = tid >> 6, lane = tid & 63, l16 = lane & 15, quad = lane >> 4;
  const int l7 = l16 & 7;
  const int wrow = (w >> 1) * 64, wcol = (w & 1) * 64;

  floatx4 acc[4][4];
#pragma unroll
  for (int i = 0; i < 4; ++i)
#pragma unroll
    for (int j = 0; j < 4; ++j) acc[i][j] = {0.f, 0.f, 0.f, 0.f};

  const int srow = tid >> 3;
  const int scol = (((tid & 7) ^ (srow & 7)) * 8);
  const unsigned short* Ap = A + (size_t)(m0 + srow) * EMBED + scol;
  const unsigned short* Bp = BT + (size_t)(n0 + srow) * EMBED + scol;

  int ab[2], bb[2];
#pragma unroll
  for (int kc = 0; kc < 2; ++kc) {
    ab[kc] = (wrow + l16) * 64 + (((4 * kc + quad) ^ l7) << 3);
    bb[kc] = (wcol + l16) * 64 + (((4 * kc + quad) ^ l7) << 3);
  }

  for (int kt = 0; kt < 16; ++kt) {
    const int k0 = kt * 64;
#pragma unroll
    for (int i = 0; i < 4; ++i)
      async16(Ap + k0 + (size_t)i * 32 * EMBED, Als + i * 2048 + tid * 8);
#pragma unroll
    for (int i = 0; i < 4; ++i)
      async16(Bp + k0 + (size_t)i * 32 * EMBED, Bls + i * 2048 + tid * 8);
    __syncthreads();
    short8 af[4][2], bf[4][2];
#pragma unroll
    for (int mt = 0; mt < 4; ++mt)
#pragma unroll
      for (int kc = 0; kc < 2; ++kc)
        af[mt][kc] = *(const short8*)(Als + ab[kc] + mt * 1024);
#pragma unroll
    for (int nt = 0; nt < 4; ++nt)
#pragma unroll
      for (int kc = 0; kc < 2; ++kc)
        bf[nt][kc] = *(const short8*)(Bls + bb[kc] + nt * 1024);
#pragma unroll
    for (int kc = 0; kc < 2; ++kc)
#pragma unroll
      for (int mt = 0; mt < 4; ++mt)
#pragma unroll
        for (int nt = 0; nt < 4; ++nt)
          acc[mt][nt] = MFMA16(af[mt][kc], bf[nt][kc], acc[mt][nt]);
    __syncthreads();
  }

  float bias[4];
#pragma unroll
  for (int nt = 0; nt < 4; ++nt) bias[nt] = bp[n0 + wcol + nt * 16 + l16];
#pragma unroll
  for (int mt = 0; mt < 4; ++mt)
#pragma unroll
    for (int r = 0; r < 4; ++r) {
      int gm = m0 + wrow + mt * 16 + quad * 4 + r;
      size_t base = (size_t)gm * EMBED + n0 + wcol;
#pragma unroll
      for (int nt = 0; nt < 4; ++nt) {
        size_t idx = base + nt * 16 + l16;
        X[idx] = acc[mt][nt][r] + bias[nt] + hid[idx];
      }
    }
}

// ---------------- in-place LayerNorm, one WAVE per row (4 rows/block) ---------
// No LDS, no __syncthreads: each wave owns a full 1024-elem row (16 f32/lane),
// 64-lane shuffle reduce.  Same math as the R9 finisher loop (passed, absmax
// 0.015625); 2048 blocks instead of 8192.
__global__ __launch_bounds__(256) void k_ln(float* __restrict__ x,
                                            const float* __restrict__ gamma,
                                            const float* __restrict__ beta) {
  const int w = threadIdx.x >> 6, lane = threadIdx.x & 63;
  const int row = blockIdx.x * 4 + w;
  float* rp = x + (size_t)row * EMBED;
  float4 xv[4];
  float s = 0.f, q = 0.f;
#pragma unroll
  for (int k = 0; k < 4; ++k) {
    xv[k] = *(const float4*)(rp + lane * 4 + k * 256);
    s += (xv[k].x + xv[k].y) + (xv[k].z + xv[k].w);
    q += (xv[k].x * xv[k].x + xv[k].y * xv[k].y) + (xv[k].z * xv[k].z + xv[k].w * xv[k].w);
  }
#pragma unroll
  for (int off = 1; off < 64; off <<= 1) {
    s += __shfl_xor(s, off);
    q += __shfl_xor(q, off);
  }
  const float mean = s * (1.f / 1024.f);
  const float var = q * (1.f / 1024.f) - mean * mean;
  const float rstd = rsqrtf(var + 1e-8f);
#pragma unroll
  for (int k = 0; k < 4; ++k) {
    const float4 g = *(const float4*)(gamma + lane * 4 + k * 256);
    const float4 be = *(const float4*)(beta + lane * 4 + k * 256);
    xv[k].x = (xv[k].x - mean) * rstd * g.x + be.x;
    xv[k].y = (xv[k].y - mean) * rstd * g.y + be.y;
    xv[k].z = (xv[k].z - mean) * rstd * g.z + be.z;
    xv[k].w = (xv[k].w - mean) * rstd * g.w + be.w;
    *(float4*)(rp + lane * 4 + k * 256) = xv[k];
  }
}

extern "C" void kernel_launch(void* const* d_in, const int* in_sizes, int n_in,
                              void* d_out, int out_size, void* d_ws, size_t ws_size,
                              hipStream_t stream) {
  const float* hid   = (const float*)d_in[0];
  const float* Wq    = (const float*)d_in[1];
  const float* bq    = (const float*)d_in[2];
  const float* Wk    = (const float*)d_in[3];
  const float* bk    = (const float*)d_in[4];
  const float* Wv    = (const float*)d_in[5];
  const float* bv    = (const float*)d_in[6];
  const float* Wp    = (const float*)d_in[7];
  const float* bp    = (const float*)d_in[8];
  const float* gamma = (const float*)d_in[9];
  const float* beta  = (const float*)d_in[10];
  float* out = (float*)d_out;

  char* ws = (char*)d_ws;
  unsigned short* hidA = (unsigned short*)ws;                          // 16 MB  [8192][1024]
  unsigned short* WT   = (unsigned short*)(ws + (size_t)(16 << 20));   //  8 MB  [4096][1024]
  unsigned short* QKV  = (unsigned short*)(ws + (size_t)(24 << 20));   // 48 MB  [8192][3072] (V third unused)
  unsigned short* VT   = (unsigned short*)(ws + (size_t)(72 << 20));   // 16 MB  [64][64][2048]
  unsigned short* CTX  = (unsigned short*)(ws + (size_t)(88 << 20));   // 16 MB  [8192][1024]

  k_prep<<<5120, 256, 0, stream>>>(hid, hidA, Wq, Wk, Wv, Wp, WT);
  k_gemm_qkv<<<dim3(64, 24), 256, 0, stream>>>(hidA, WT, bq, bk, bv, QKV, VT);
  k_attn<<<dim3(64, 8), 256, 0, stream>>>(QKV, VT, CTX);
  k_gemm_proj<<<dim3(64, 8), 256, 0, stream>>>(CTX, WT + (size_t)3 * EMBED * EMBED, bp, hid, out);
  k_ln<<<2048, 256, 0, stream>>>(out, gamma, beta);
}